// Round 3
// baseline (55377.075 us; speedup 1.0000x reference)
//
#include <hip/hip_runtime.h>

#define IN_   16
#define HID_  50
#define G4_   200   // 4*HID
#define T_    128
#define NCLS_ 20
#define BPB_  16    // batches per block
#define NTHR_ 256
#define WPAD_ 51    // W_hh LDS row stride (odd -> conflict-free)
#define GPAD_ 17    // gate LDS row stride (odd -> conflict-free)

__device__ __forceinline__ float fast_sigmoid(float v) {
    float e = __expf(-v);
    return __builtin_amdgcn_rcpf(1.0f + e);
}
__device__ __forceinline__ float fast_tanh(float v) {
    float e = __expf(2.0f * v);
    return fmaf(-2.0f, __builtin_amdgcn_rcpf(e + 1.0f), 1.0f);
}

#define REP16(OP) OP(0) OP(1) OP(2) OP(3) OP(4) OP(5) OP(6) OP(7) \
                  OP(8) OP(9) OP(10) OP(11) OP(12) OP(13) OP(14) OP(15)

// 16 batch-fmas from one LDS row into NAMED scalar accumulators a0..a15
// (no private arrays anywhere in the hot path -> nothing can land in scratch)
#define FMA16(RPTR, W) do {                                              \
    const float4* _r = (const float4*)(RPTR);                            \
    const float4 _r0 = _r[0], _r1 = _r[1], _r2 = _r[2], _r3 = _r[3];     \
    a0  = fmaf(_r0.x,(W),a0);  a1  = fmaf(_r0.y,(W),a1);                 \
    a2  = fmaf(_r0.z,(W),a2);  a3  = fmaf(_r0.w,(W),a3);                 \
    a4  = fmaf(_r1.x,(W),a4);  a5  = fmaf(_r1.y,(W),a5);                 \
    a6  = fmaf(_r1.z,(W),a6);  a7  = fmaf(_r1.w,(W),a7);                 \
    a8  = fmaf(_r2.x,(W),a8);  a9  = fmaf(_r2.y,(W),a9);                 \
    a10 = fmaf(_r2.z,(W),a10); a11 = fmaf(_r2.w,(W),a11);                \
    a12 = fmaf(_r3.x,(W),a12); a13 = fmaf(_r3.y,(W),a13);                \
    a14 = fmaf(_r3.z,(W),a14); a15 = fmaf(_r3.w,(W),a15);                \
} while (0)

__global__ __launch_bounds__(NTHR_, 2)
void lstm_fused(const float* __restrict__ x,
                const float* __restrict__ W_ih,
                const float* __restrict__ W_hh,
                const float* __restrict__ b_ih,
                const float* __restrict__ b_hh,
                const float* __restrict__ W_fc,
                const float* __restrict__ b_fc,
                float* __restrict__ out)
{
    // h/x laid out [feature][batch] so gate threads read rows as broadcast float4s.
    __shared__ __align__(16) float h_lds[HID_][BPB_];
    __shared__ __align__(16) float x_lds[IN_][BPB_];
    __shared__ float g_lds[G4_][GPAD_];     // scalar r/w, odd stride -> conflict-free
    __shared__ float whh_lds[G4_ * WPAD_];  // W_hh rows, stride 51

    const int tid = threadIdx.x;
    const int b0  = blockIdx.x * BPB_;

    // ---- stage W_hh into LDS once
    for (int idx = tid; idx < G4_ * HID_; idx += NTHR_) {
        const int r = idx / HID_;
        const int c = idx - r * HID_;
        whh_lds[r * WPAD_ + c] = W_hh[idx];
    }

    // ---- gate-thread persistent state: W_ih row + bias as NAMED scalars
    float wi0=0,wi1=0,wi2=0,wi3=0,wi4=0,wi5=0,wi6=0,wi7=0,
          wi8=0,wi9=0,wi10=0,wi11=0,wi12=0,wi13=0,wi14=0,wi15=0;
    float bias = 0.0f;
    if (tid < G4_) {
        const float4* wp = (const float4*)(W_ih + tid * IN_);
        const float4 w0 = wp[0], w1 = wp[1], w2 = wp[2], w3 = wp[3];
        wi0=w0.x;  wi1=w0.y;  wi2=w0.z;  wi3=w0.w;
        wi4=w1.x;  wi5=w1.y;  wi6=w1.z;  wi7=w1.w;
        wi8=w2.x;  wi9=w2.y;  wi10=w2.z; wi11=w2.w;
        wi12=w3.x; wi13=w3.y; wi14=w3.z; wi15=w3.w;
        bias = b_ih[tid] + b_hh[tid];
    }

    // ---- update-thread state: unit uk = tid/4, batches ub..ub+3, c in registers
    const int uk = tid >> 2;
    const int ub = (tid & 3) << 2;
    float c0 = 0.f, c1 = 0.f, c2 = 0.f, c3 = 0.f;

    // zero h
    for (int idx = tid; idx < HID_ * BPB_; idx += NTHR_)
        ((float*)h_lds)[idx] = 0.0f;

    // ---- x loader mapping: 256 threads = 16 batches x 16 features, one elem/step
    const int xb = tid >> 4;
    const int xi = tid & 15;
    const float* xp = x + (size_t)(b0 + xb) * (T_ * IN_) + xi;
    x_lds[xi][xb] = xp[0];
    __syncthreads();

    const float* wr = &whh_lds[tid * WPAD_];   // this gate's W_hh row (LDS)

    for (int t = 0; t < T_; ++t) {
        // prefetch next step's x element (hidden under compute)
        float xv_next = 0.0f;
        if (t + 1 < T_) xv_next = xp[(size_t)(t + 1) * IN_];

        if (tid < G4_) {
            float a0,a1,a2,a3,a4,a5,a6,a7,a8,a9,a10,a11,a12,a13,a14,a15;
            #define INIT1(k) a##k = bias;
            REP16(INIT1)
            #undef INIT1

            // input projection: 16 rows, weights are named scalars
            #define FI(k) FMA16(&x_lds[k][0], wi##k);
            REP16(FI)
            #undef FI

            // recurrent matmul: 50 rows, weight from LDS
            #pragma unroll
            for (int j = 0; j < HID_; ++j) {
                const float w = wr[j];
                FMA16(&h_lds[j][0], w);
            }

            // activation in place: 0..99 = i,f (sigmoid), 100..149 = g (tanh), 150..199 = o
            const bool isg = (tid >= 100) && (tid < 150);
            #define ACT1(k) a##k = isg ? fast_tanh(a##k) : fast_sigmoid(a##k);
            REP16(ACT1)
            #undef ACT1

            #define ST1(k) g_lds[tid][k] = a##k;
            REP16(ST1)
            #undef ST1
        }
        __syncthreads();   // gates ready

        if (tid < G4_) {
            const float i0 = g_lds[uk      ][ub+0], i1 = g_lds[uk      ][ub+1],
                        i2 = g_lds[uk      ][ub+2], i3 = g_lds[uk      ][ub+3];
            const float f0 = g_lds[ 50 + uk][ub+0], f1 = g_lds[ 50 + uk][ub+1],
                        f2 = g_lds[ 50 + uk][ub+2], f3 = g_lds[ 50 + uk][ub+3];
            const float g0 = g_lds[100 + uk][ub+0], g1 = g_lds[100 + uk][ub+1],
                        g2 = g_lds[100 + uk][ub+2], g3 = g_lds[100 + uk][ub+3];
            const float o0 = g_lds[150 + uk][ub+0], o1 = g_lds[150 + uk][ub+1],
                        o2 = g_lds[150 + uk][ub+2], o3 = g_lds[150 + uk][ub+3];
            c0 = fmaf(f0, c0, i0 * g0);
            c1 = fmaf(f1, c1, i1 * g1);
            c2 = fmaf(f2, c2, i2 * g2);
            c3 = fmaf(f3, c3, i3 * g3);
            float4 hv;
            hv.x = o0 * fast_tanh(c0);
            hv.y = o1 * fast_tanh(c1);
            hv.z = o2 * fast_tanh(c2);
            hv.w = o3 * fast_tanh(c3);
            *(float4*)(&h_lds[uk][ub]) = hv;
        }
        x_lds[xi][xb] = xv_next;   // x_lds already consumed before barrier above
        __syncthreads();           // h + next x ready
    }

    // ---- FC head: 16 batches x 20 classes per block
    for (int p = tid; p < BPB_ * NCLS_; p += NTHR_) {
        const int b  = p / NCLS_;
        const int cl = p % NCLS_;
        float acc = b_fc[cl];
        #pragma unroll
        for (int j = 0; j < HID_; ++j) {
            float hv = fmaxf(h_lds[j][b], 0.0f);   // relu
            acc = fmaf(hv, W_fc[cl * HID_ + j], acc);
        }
        out[(size_t)(b0 + b) * NCLS_ + cl] = acc;
    }
}

extern "C" void kernel_launch(void* const* d_in, const int* in_sizes, int n_in,
                              void* d_out, int out_size, void* d_ws, size_t ws_size,
                              hipStream_t stream) {
    const float* x    = (const float*)d_in[0];
    const float* W_ih = (const float*)d_in[1];
    const float* W_hh = (const float*)d_in[2];
    const float* b_ih = (const float*)d_in[3];
    const float* b_hh = (const float*)d_in[4];
    const float* W_fc = (const float*)d_in[5];
    const float* b_fc = (const float*)d_in[6];
    float* out = (float*)d_out;

    const int B = in_sizes[0] / (T_ * IN_);   // 8192
    dim3 grid(B / BPB_), block(NTHR_);
    hipLaunchKernelGGL(lstm_fused, grid, block, 0, stream,
                       x, W_ih, W_hh, b_ih, b_hh, W_fc, b_fc, out);
}

// Round 4
// 878.325 us; speedup vs baseline: 63.0485x; 63.0485x over previous
//
#include <hip/hip_runtime.h>

#define IN_   16
#define HID_  50
#define G4_   200   // 4*HID
#define T_    128
#define NCLS_ 20
#define BPB_  16    // batches per block
#define NTHR_ 256
#define WPAD_ 51    // W_hh LDS row stride (odd -> conflict-free)
#define IPAD_ 17    // W_ih LDS row stride
#define GPAD_ 17    // gate LDS row stride

__device__ __forceinline__ float fast_sigmoid(float v) {
    float e = __expf(-v);
    return __builtin_amdgcn_rcpf(1.0f + e);
}
__device__ __forceinline__ float fast_tanh(float v) {
    float e = __expf(2.0f * v);
    return fmaf(-2.0f, __builtin_amdgcn_rcpf(e + 1.0f), 1.0f);
}

#define REP16(OP) OP(0) OP(1) OP(2) OP(3) OP(4) OP(5) OP(6) OP(7) \
                  OP(8) OP(9) OP(10) OP(11) OP(12) OP(13) OP(14) OP(15)

// 16 batch-fmas from one LDS row into named scalar accumulators a0..a15
#define FMA16(RPTR, W) do {                                              \
    const float4* _r = (const float4*)(RPTR);                            \
    const float4 _r0 = _r[0], _r1 = _r[1], _r2 = _r[2], _r3 = _r[3];     \
    a0  = fmaf(_r0.x,(W),a0);  a1  = fmaf(_r0.y,(W),a1);                 \
    a2  = fmaf(_r0.z,(W),a2);  a3  = fmaf(_r0.w,(W),a3);                 \
    a4  = fmaf(_r1.x,(W),a4);  a5  = fmaf(_r1.y,(W),a5);                 \
    a6  = fmaf(_r1.z,(W),a6);  a7  = fmaf(_r1.w,(W),a7);                 \
    a8  = fmaf(_r2.x,(W),a8);  a9  = fmaf(_r2.y,(W),a9);                 \
    a10 = fmaf(_r2.z,(W),a10); a11 = fmaf(_r2.w,(W),a11);                \
    a12 = fmaf(_r3.x,(W),a12); a13 = fmaf(_r3.y,(W),a13);                \
    a14 = fmaf(_r3.z,(W),a14); a15 = fmaf(_r3.w,(W),a15);                \
} while (0)

// NOTE: no min-waves arg — occupancy is LDS-capped at 2 blocks/CU anyway;
// freeing the VGPR ceiling prevents the scheduler-window spill seen in R1-R3
// (VGPR_Count pinned at 128 + 145 GB scratch traffic).
__global__ __launch_bounds__(NTHR_)
void lstm_fused(const float* __restrict__ x,
                const float* __restrict__ W_ih,
                const float* __restrict__ W_hh,
                const float* __restrict__ b_ih,
                const float* __restrict__ b_hh,
                const float* __restrict__ W_fc,
                const float* __restrict__ b_fc,
                float* __restrict__ out)
{
    __shared__ __align__(16) float h_lds[HID_][BPB_];
    __shared__ __align__(16) float x_lds[IN_][BPB_];
    __shared__ float g_lds[G4_][GPAD_];     // odd stride -> conflict-free
    __shared__ float whh_lds[G4_ * WPAD_];  // W_hh rows, stride 51
    __shared__ float wih_lds[G4_ * IPAD_];  // W_ih rows, stride 17

    const int tid = threadIdx.x;
    const int b0  = blockIdx.x * BPB_;

    // ---- stage weights into LDS once
    for (int idx = tid; idx < G4_ * HID_; idx += NTHR_) {
        const int r = idx / HID_;
        const int c = idx - r * HID_;
        whh_lds[r * WPAD_ + c] = W_hh[idx];
    }
    for (int idx = tid; idx < G4_ * IN_; idx += NTHR_) {
        const int r = idx >> 4;
        const int c = idx & 15;
        wih_lds[r * IPAD_ + c] = W_ih[idx];
    }

    float bias = 0.0f;
    if (tid < G4_) bias = b_ih[tid] + b_hh[tid];

    // ---- update-thread state: unit uk = tid/4, batches ub..ub+3, c in registers
    const int uk = tid >> 2;
    const int ub = (tid & 3) << 2;
    float c0 = 0.f, c1 = 0.f, c2 = 0.f, c3 = 0.f;

    for (int idx = tid; idx < HID_ * BPB_; idx += NTHR_)
        ((float*)h_lds)[idx] = 0.0f;

    // ---- x loader mapping: 256 threads = 16 batches x 16 features
    const int xb = tid >> 4;
    const int xi = tid & 15;
    const float* xp = x + (size_t)(b0 + xb) * (T_ * IN_) + xi;
    x_lds[xi][xb] = xp[0];
    __syncthreads();

    const float* wr  = &whh_lds[tid * WPAD_];
    const float* wir = &wih_lds[tid * IPAD_];

    for (int t = 0; t < T_; ++t) {
        float xv_next = 0.0f;
        if (t + 1 < T_) xv_next = xp[(size_t)(t + 1) * IN_];

        if (tid < G4_) {
            float a0,a1,a2,a3,a4,a5,a6,a7,a8,a9,a10,a11,a12,a13,a14,a15;
            #define INIT1(k) a##k = bias;
            REP16(INIT1)
            #undef INIT1

            // input projection: bounded unroll keeps the scheduling window
            // (and thus register demand) small -> no spill
            #pragma unroll 4
            for (int i = 0; i < IN_; ++i) {
                const float w = wir[i];
                FMA16(&x_lds[i][0], w);
            }
            // recurrent matmul
            #pragma unroll 4
            for (int j = 0; j < HID_; ++j) {
                const float w = wr[j];
                FMA16(&h_lds[j][0], w);
            }

            const bool isg = (tid >= 100) && (tid < 150);
            #define ACT1(k) a##k = isg ? fast_tanh(a##k) : fast_sigmoid(a##k);
            REP16(ACT1)
            #undef ACT1

            #define ST1(k) g_lds[tid][k] = a##k;
            REP16(ST1)
            #undef ST1
        }
        __syncthreads();   // gates ready

        if (tid < G4_) {
            const float i0 = g_lds[uk      ][ub+0], i1 = g_lds[uk      ][ub+1],
                        i2 = g_lds[uk      ][ub+2], i3 = g_lds[uk      ][ub+3];
            const float f0 = g_lds[ 50 + uk][ub+0], f1 = g_lds[ 50 + uk][ub+1],
                        f2 = g_lds[ 50 + uk][ub+2], f3 = g_lds[ 50 + uk][ub+3];
            const float g0 = g_lds[100 + uk][ub+0], g1 = g_lds[100 + uk][ub+1],
                        g2 = g_lds[100 + uk][ub+2], g3 = g_lds[100 + uk][ub+3];
            const float o0 = g_lds[150 + uk][ub+0], o1 = g_lds[150 + uk][ub+1],
                        o2 = g_lds[150 + uk][ub+2], o3 = g_lds[150 + uk][ub+3];
            c0 = fmaf(f0, c0, i0 * g0);
            c1 = fmaf(f1, c1, i1 * g1);
            c2 = fmaf(f2, c2, i2 * g2);
            c3 = fmaf(f3, c3, i3 * g3);
            float4 hv;
            hv.x = o0 * fast_tanh(c0);
            hv.y = o1 * fast_tanh(c1);
            hv.z = o2 * fast_tanh(c2);
            hv.w = o3 * fast_tanh(c3);
            *(float4*)(&h_lds[uk][ub]) = hv;
        }
        x_lds[xi][xb] = xv_next;
        __syncthreads();           // h + next x ready
    }

    // ---- FC head: 16 batches x 20 classes per block
    for (int p = tid; p < BPB_ * NCLS_; p += NTHR_) {
        const int b  = p / NCLS_;
        const int cl = p % NCLS_;
        float acc = b_fc[cl];
        #pragma unroll
        for (int j = 0; j < HID_; ++j) {
            float hv = fmaxf(h_lds[j][b], 0.0f);   // relu
            acc = fmaf(hv, W_fc[cl * HID_ + j], acc);
        }
        out[(size_t)(b0 + b) * NCLS_ + cl] = acc;
    }
}

extern "C" void kernel_launch(void* const* d_in, const int* in_sizes, int n_in,
                              void* d_out, int out_size, void* d_ws, size_t ws_size,
                              hipStream_t stream) {
    const float* x    = (const float*)d_in[0];
    const float* W_ih = (const float*)d_in[1];
    const float* W_hh = (const float*)d_in[2];
    const float* b_ih = (const float*)d_in[3];
    const float* b_hh = (const float*)d_in[4];
    const float* W_fc = (const float*)d_in[5];
    const float* b_fc = (const float*)d_in[6];
    float* out = (float*)d_out;

    const int B = in_sizes[0] / (T_ * IN_);   // 8192
    dim3 grid(B / BPB_), block(NTHR_);
    hipLaunchKernelGGL(lstm_fused, grid, block, 0, stream,
                       x, W_ih, W_hh, b_ih, b_hh, W_fc, b_fc, out);
}